// Round 7
// baseline (1012.488 us; speedup 1.0000x reference)
//
#include <hip/hip_runtime.h>
#include <math.h>

// Problem constants
#define TT 4
#define BB 16
#define CC 256
#define NN 1024
#define NT 16       // spatial positions per block
#define COLS 64     // 4 t * 16 n  (col = t*16 + n = lane)
#define ROWP 68     // padded xs row stride in dwords: 16B-aligned, bank-spread
#define EPSF 1e-5f

// 4-step LIF chain, tau=2 hard-reset (v_reset=0), spike = (h >= th).
// h = v + (x - v)/2 exactly as reference (div by 2 == *0.5, exact).
__device__ __forceinline__ void lif4(const float xin[4], float th, float s[4]) {
  float v = 0.f;
  #pragma unroll
  for (int t = 0; t < 4; ++t) {
    const float h = v + (xin[t] - v) * 0.5f;
    const bool f = (h >= th);
    s[t] = f ? 1.f : 0.f;
    v = f ? 0.f : h;
  }
}

// select s[tl] with compile-time indices only (rule #20)
__device__ __forceinline__ float sel4(const float s[4], int tl) {
  return tl == 0 ? s[0] : tl == 1 ? s[1] : tl == 2 ? s[2] : s[3];
}

// 16-output-channel GEMM slab: acc[r] = sum_c w[o16+r][c] * xs[c][lane].
// Weight addresses are wave-uniform -> compiler scalarizes to s_load (K$ path,
// no vector-L1 traffic, no per-lane address math). FMA = v_fmac(s, v, acc).
// xf[16] register-cached per c-block, reused by all 16 rows -> LDS reads /16.
// c ascends (cb outer, j inner): fmaf chain bit-identical to rounds 1-6.
__device__ __forceinline__ void gemm16(const float* __restrict__ w, const float* xs,
                                       int o16, int lane, float acc[16]) {
  #pragma unroll
  for (int r = 0; r < 16; ++r) acc[r] = 0.f;
  #pragma unroll 1
  for (int cb = 0; cb < 16; ++cb) {
    float xf[16];
    #pragma unroll
    for (int j = 0; j < 16; ++j) xf[j] = xs[(cb * 16 + j) * ROWP + lane];
    #pragma unroll
    for (int r = 0; r < 16; ++r) {
      const float* wr = w + (size_t)(o16 + r) * CC + cb * 16;  // uniform
      #pragma unroll
      for (int j = 0; j < 16; ++j) acc[r] = fmaf(wr[j], xf[j], acc[r]);
    }
  }
}

// 256 thr = 4 waves; lane=col (t,n); wave w owns channels [64w,64w+64) = heads
// {2w, 2w+1}. LDS 68KB -> 2 blocks/CU; low occupancy is intentional (the
// limiter was the shared vector-L1 weight path, now moved to scalar K$).
__global__ __launch_bounds__(256, 2)
void pushpull_fused7(const float* __restrict__ x,
                     const float* __restrict__ q_w, const float* __restrict__ q_gamma,
                     const float* __restrict__ q_beta, const float* __restrict__ q_mean,
                     const float* __restrict__ q_var,
                     const float* __restrict__ k_w, const float* __restrict__ k_gamma,
                     const float* __restrict__ k_beta, const float* __restrict__ k_mean,
                     const float* __restrict__ k_var,
                     const float* __restrict__ proj_w, const float* __restrict__ proj_b,
                     const float* __restrict__ p_gamma, const float* __restrict__ p_beta,
                     const float* __restrict__ p_mean, const float* __restrict__ p_var,
                     float* __restrict__ out) {
  __shared__ float xs[CC * ROWP];   // 68 KB: xs[c][col], stride 68 dwords

  const int tid  = threadIdx.x;
  // Chunked XCD swizzle (bijective: 1024 = 8*128)
  const int bid  = (int)blockIdx.x;
  const int lid  = ((bid & 7) << 7) | (bid >> 3);
  const int b    = lid >> 6;                  // 16 batches
  const int n0   = (lid & 63) * NT;           // 64 spatial tiles of 16
  const int lane = tid & 63;
  const int wv   = __builtin_amdgcn_readfirstlane(tid >> 6);
  const int tl   = lane >> 4;                 // this lane's timestep
  const int nl   = lane & 15;                 // this lane's spatial offset
  const int ob   = wv * 64;                   // wave's channel base

  // ---- Stage x tile: float4 global (full 64B lines) -> b128 LDS writes ----
  #pragma unroll
  for (int rep = 0; rep < 16; ++rep) {
    const int s4 = rep * 256 + tid;
    const int c  = s4 >> 4;
    const int t  = (s4 >> 2) & 3;
    const int k  = (s4 & 3) * 4;
    const float4 v = *reinterpret_cast<const float4*>(
        x + (((size_t)t * BB + b) * CC + c) * NN + n0 + k);
    *reinterpret_cast<float4*>(&xs[c * ROWP + t * 16 + k]) = v;
  }
  __syncthreads();

  float d0 = 0.f, d1 = 0.f;          // push-pull sums per head (exact ints)
  unsigned long long ks = 0ull;      // k-spike mask, bit = local channel

  // ---- q pass: GEMM + BN + push/pull LIFs -> per-head sums ----
  #pragma unroll 1
  for (int og = 0; og < 4; ++og) {
    float acc[16];
    gemm16(q_w, xs, ob + og * 16, lane, acc);
    float dsum = 0.f;
    #pragma unroll
    for (int i = 0; i < 16; ++i) {
      const int o = ob + og * 16 + i;
      const float inv = q_gamma[o] / sqrtf(q_var[o] + EPSF);   // scalar loads
      const float qv = (acc[i] - q_mean[o]) * inv + q_beta[o];
      float qt[4], nqt[4], se[4], si[4];
      qt[0] = __shfl(qv, nl);      qt[1] = __shfl(qv, nl + 16);
      qt[2] = __shfl(qv, nl + 32); qt[3] = __shfl(qv, nl + 48);
      #pragma unroll
      for (int t = 0; t < 4; ++t) nqt[t] = -qt[t];
      lif4(qt,  1.0f, se);
      lif4(nqt, 1.0f, si);
      dsum += sel4(se, tl) - sel4(si, tl);
    }
    if (og < 2) d0 += dsum; else d1 += dsum;   // uniform branch
  }

  // ---- k pass: GEMM + BN + LIF -> binary mask ----
  #pragma unroll 1
  for (int og = 0; og < 4; ++og) {
    float acc[16];
    gemm16(k_w, xs, ob + og * 16, lane, acc);
    #pragma unroll
    for (int i = 0; i < 16; ++i) {
      const int o = ob + og * 16 + i;
      const float inv = k_gamma[o] / sqrtf(k_var[o] + EPSF);
      const float kv = (acc[i] - k_mean[o]) * inv + k_beta[o];
      float kt[4], sk[4];
      kt[0] = __shfl(kv, nl);      kt[1] = __shfl(kv, nl + 16);
      kt[2] = __shfl(kv, nl + 32); kt[3] = __shfl(kv, nl + 48);
      lif4(kt, 1.0f, sk);
      ks |= (unsigned long long)(sel4(sk, tl) != 0.f) << (og * 16 + i);
    }
  }

  // ---- attention gate per head: lif(d, th=0.5) over t ----
  float at0, at1;
  {
    float a[4], s[4];
    a[0] = __shfl(d0, nl);      a[1] = __shfl(d0, nl + 16);
    a[2] = __shfl(d0, nl + 32); a[3] = __shfl(d0, nl + 48);
    lif4(a, 0.5f, s);
    at0 = sel4(s, tl);
    a[0] = __shfl(d1, nl);      a[1] = __shfl(d1, nl + 16);
    a[2] = __shfl(d1, nl + 32); a[3] = __shfl(d1, nl + 48);
    lif4(a, 0.5f, s);
    at1 = sel4(s, tl);
  }

  __syncthreads();  // all waves done reading xs
  // ---- x_one = attn & k_s (binary), overwrite own rows (conflict-free) ----
  #pragma unroll 1
  for (int oi = 0; oi < 64; ++oi) {
    const float v = ((ks >> oi) & 1ull) ? (oi < 32 ? at0 : at1) : 0.f;
    xs[(ob + oi) * ROWP + lane] = v;
  }
  __syncthreads();

  // ---- proj pass: GEMM + bias + BN + final LIF + full-line stores ----
  #pragma unroll 1
  for (int og = 0; og < 4; ++og) {
    float acc[16];
    gemm16(proj_w, xs, ob + og * 16, lane, acc);
    #pragma unroll
    for (int i = 0; i < 16; ++i) {
      const int o = ob + og * 16 + i;
      const float inv = p_gamma[o] / sqrtf(p_var[o] + EPSF);
      const float pv = ((acc[i] + proj_b[o]) - p_mean[o]) * inv + p_beta[o];
      float pt[4], sp[4];
      pt[0] = __shfl(pv, nl);      pt[1] = __shfl(pv, nl + 16);
      pt[2] = __shfl(pv, nl + 32); pt[3] = __shfl(pv, nl + 48);
      lif4(pt, 1.0f, sp);
      out[(((size_t)tl * BB + b) * CC + o) * NN + n0 + nl] = sel4(sp, tl);
    }
  }
}

extern "C" void kernel_launch(void* const* d_in, const int* in_sizes, int n_in,
                              void* d_out, int out_size, void* d_ws, size_t ws_size,
                              hipStream_t stream) {
  const float* x       = (const float*)d_in[0];
  const float* q_w     = (const float*)d_in[1];
  const float* q_gamma = (const float*)d_in[2];
  const float* q_beta  = (const float*)d_in[3];
  const float* q_mean  = (const float*)d_in[4];
  const float* q_var   = (const float*)d_in[5];
  const float* k_w     = (const float*)d_in[6];
  const float* k_gamma = (const float*)d_in[7];
  const float* k_beta  = (const float*)d_in[8];
  const float* k_mean  = (const float*)d_in[9];
  const float* k_var   = (const float*)d_in[10];
  const float* proj_w  = (const float*)d_in[11];
  const float* proj_b  = (const float*)d_in[12];
  const float* p_gamma = (const float*)d_in[13];
  const float* p_beta  = (const float*)d_in[14];
  const float* p_mean  = (const float*)d_in[15];
  const float* p_var   = (const float*)d_in[16];
  float* out = (float*)d_out;

  dim3 grid(BB * (NN / NT));   // 16 * 64 = 1024 blocks
  dim3 block(256);             // 4 waves; wave = 64 channels = 2 heads
  pushpull_fused7<<<grid, block, 0, stream>>>(
      x, q_w, q_gamma, q_beta, q_mean, q_var,
      k_w, k_gamma, k_beta, k_mean, k_var,
      proj_w, proj_b, p_gamma, p_beta, p_mean, p_var, out);
}